// Round 2
// baseline (333.071 us; speedup 1.0000x reference)
//
#include <hip/hip_runtime.h>

// out[b, i*16+j, d, l] = sum_ks s[b,(j-i)&15,l,ks] * t[b,j,l,d-ks], d in [0,125); 0 for d>=125.
// B=32, N=16, L=64, D_in=63, D_out=128. Output 32*256*128*64 fp32 = 256 MB.
//
// Block = 256 threads = 4 waves, fixed (b,k). All waves share the s-slice (b,k);
// wave w handles j = jg*4+w, i = (j-k)&15 with its own t-slice. Slices staged in
// LDS via coalesced float4 copies (R0's 252B-lane-stride scalar gathers fragmented
// into ~64 transactions/instr and dominated runtime). Flat stride-63 LDS rows are
// bank-conflict-free (63 odd: bank = (c - l) % 32). LDS = 5*15.75 KB = 80.6 KB ->
// 2 blocks/CU. Conv itself is register-resident: 63*63 = 3969 v_fma_f32 per lane,
// 16 independent accumulators per d-chunk. Stores coalesced over l (lane = l).

#define D_IN 63
#define L_DIM 64
#define N_DIM 16
#define DP 128
#define SLICE (L_DIM * D_IN)   // 4032 floats = 15.75 KB

__global__ __launch_bounds__(256, 2) void conv_kernel(
    const float* __restrict__ s, const float* __restrict__ t,
    float* __restrict__ out)
{
    __shared__ float lds_s[SLICE];
    __shared__ float lds_t[4][SLICE];

    const int tid  = threadIdx.x;
    const int w    = tid >> 6;     // wave id 0..3
    const int lane = tid & 63;     // l

    // blockIdx.x = b*64 + k*4 + jg
    const int blk = blockIdx.x;
    const int b   = blk >> 6;
    const int k   = (blk >> 2) & 15;
    const int jg  = blk & 3;
    const int j   = jg * 4 + w;
    const int i   = (j - k) & 15;

    // Cooperative coalesced staging: s-slice (b,k) + 4 t-slices (b, jg*4+ws).
    {
        const float4* __restrict__ sp =
            (const float4*)(s + (size_t)(b * N_DIM + k) * SLICE);
        float4* ls4 = (float4*)lds_s;
        for (int e = tid; e < SLICE / 4; e += 256) ls4[e] = sp[e];
#pragma unroll
        for (int ws = 0; ws < 4; ++ws) {
            const float4* __restrict__ tp =
                (const float4*)(t + (size_t)(b * N_DIM + jg * 4 + ws) * SLICE);
            float4* lt4 = (float4*)lds_t[ws];
            for (int e = tid; e < SLICE / 4; e += 256) lt4[e] = tp[e];
        }
    }
    __syncthreads();

    float sv[D_IN], tv[D_IN];
#pragma unroll
    for (int c = 0; c < D_IN; ++c) sv[c] = lds_s[lane * D_IN + c];
#pragma unroll
    for (int c = 0; c < D_IN; ++c) tv[c] = lds_t[w][lane * D_IN + c];

    float* __restrict__ orow =
        out + (size_t)((b * N_DIM + i) * N_DIM + j) * (DP * L_DIM) + lane;

#pragma unroll
    for (int d0 = 0; d0 < DP; d0 += 16) {
        float acc[16];
#pragma unroll
        for (int dd = 0; dd < 16; ++dd) acc[dd] = 0.0f;

#pragma unroll
        for (int ks = 0; ks < D_IN; ++ks) {
#pragma unroll
            for (int dd = 0; dd < 16; ++dd) {
                const int kt = d0 + dd - ks;           // compile-time constant
                if (kt >= 0 && kt < D_IN)
                    acc[dd] += sv[ks] * tv[kt];
            }
        }

#pragma unroll
        for (int dd = 0; dd < 16; ++dd)
            orow[(size_t)(d0 + dd) * L_DIM] = acc[dd];
    }
}

extern "C" void kernel_launch(void* const* d_in, const int* in_sizes, int n_in,
                              void* d_out, int out_size, void* d_ws, size_t ws_size,
                              hipStream_t stream) {
    const float* s = (const float*)d_in[0];
    const float* t = (const float*)d_in[1];
    float* out = (float*)d_out;
    // grid = B * N * (N/4) = 32 * 16 * 4 = 2048 blocks of 256 threads
    hipLaunchKernelGGL(conv_kernel, dim3(32 * N_DIM * 4), dim3(256), 0, stream,
                       s, t, out);
}